// Round 4
// baseline (602.695 us; speedup 1.0000x reference)
//
#include <hip/hip_runtime.h>
#include <hip/hip_bf16.h>

// SimpleMultiheadAttention on gfx950.
// d_in: 0 query1,1 query2,2 key,3 value, then (Wq,bq),(Wq2,bq2),(Wq3,bq3),(Wk,bk),(Wv,bv),(Wo,bo)
// d_out: output [2,1024,1024] fp32 then a1 [2,16,1024,1024] fp32.
// bf16 MFMA everywhere; global softmax via sum-pass + recompute-pass.
// R4: attn_main split over the 3 Q-matrices (768 blocks, no pc[] accumulation,
// Q-frags hoisted to regs, 3 waves/SIMD); O = sum of 3 partials via tiny combine
// kernel; outproj back to K=1024; sums 4-way s-split (4 waves/SIMD, Q-hoisted).

#define B_ 2
#define T_ 1024
#define E_ 1024
#define H_ 16
#define HD_ 64
#define BH_ 32

// 0.125 (1/sqrt(64)) / 0.5 (TEMP) * log2(e)
#define CEXP 0.36067376022224085f

typedef float f32x4 __attribute__((ext_vector_type(4)));
typedef short bfrag __attribute__((ext_vector_type(8)));   // 8 x bf16

__device__ __forceinline__ unsigned short f2b(float f) {
  unsigned int u = __float_as_uint(f);
  u += 0x7fffu + ((u >> 16) & 1u);          // RNE (inputs finite)
  return (unsigned short)(u >> 16);
}

__device__ __forceinline__ float b2f(unsigned short u) {
  return __uint_as_float((unsigned int)u << 16);
}

// single-instruction 2^x (inputs finite, |x| modest -> no denormal fixup needed)
__device__ __forceinline__ float fexp2(float x) {
  float r;
  asm("v_exp_f32 %0, %1" : "=v"(r) : "v"(x));
  return r;
}

// global -> LDS direct 16B copy.
__device__ __forceinline__ void gl_lds16(const unsigned short* g, unsigned short* l) {
  __builtin_amdgcn_global_load_lds(
      reinterpret_cast<const __attribute__((address_space(1))) unsigned int*>(
          reinterpret_cast<uintptr_t>(g)),
      reinterpret_cast<__attribute__((address_space(3))) unsigned int*>(
          reinterpret_cast<uintptr_t>(l)),
      16, 0, 0);
}

// ---------------------------------------------------------------- convert
struct CvtArgs { const float* src[10]; unsigned short* dst[10]; int n[10]; };

__global__ __launch_bounds__(256) void cvt_kernel(CvtArgs a) {
  const int z = blockIdx.y;
  const float* __restrict__ s = a.src[z];
  unsigned short* __restrict__ d = a.dst[z];
  const int n = a.n[z];
  const int stride = gridDim.x * 256 * 4;
  for (int i = (blockIdx.x * 256 + threadIdx.x) * 4; i < n; i += stride) {
    float4 v = *(const float4*)(s + i);
    ushort4 o;
    o.x = f2b(v.x); o.y = f2b(v.y); o.z = f2b(v.z); o.w = f2b(v.w);
    *(ushort4*)(d + i) = o;
  }
}

// ---------------------------------------------------------------- GEMM core
// C[128x128] tile of A * W^T (both row-major [row][KLEN] bf16).
// m97 structure: global_load_lds dwordx4 stage -> drain barrier -> ds_read+MFMA.
template <int KLEN>
__device__ __forceinline__ void mm128_core(const unsigned short* __restrict__ A,
                                           const unsigned short* __restrict__ W,
                                           int m0, int n0,
                                           unsigned short* As, unsigned short* Bs,
                                           f32x4 acc[4][4]) {
  const int tid  = threadIdx.x;
  const int lane = tid & 63, w = tid >> 6;
  const int lrow = lane & 15, quad = lane >> 4;
  const int wm = (w >> 1) * 64, wn = (w & 1) * 64;
  const int srow = tid >> 2, soff = (tid & 3) * 8;   // 8 bf16 = 16B per load

  const unsigned short* Ar0 = A + (size_t)(m0 + srow) * KLEN + soff;
  const unsigned short* Ar1 = Ar0 + (size_t)64 * KLEN;
  const unsigned short* Br0 = W + (size_t)(n0 + srow) * KLEN + soff;
  const unsigned short* Br1 = Br0 + (size_t)64 * KLEN;
  unsigned short* Ad0 = As + tid * 8;
  unsigned short* Ad1 = As + 2048 + tid * 8;
  unsigned short* Bd0 = Bs + tid * 8;
  unsigned short* Bd1 = Bs + 2048 + tid * 8;

  for (int k0 = 0; k0 < KLEN; k0 += 32) {
    __syncthreads();                       // prev-iter LDS reads done
    gl_lds16(Ar0 + k0, Ad0);
    gl_lds16(Ar1 + k0, Ad1);
    gl_lds16(Br0 + k0, Bd0);
    gl_lds16(Br1 + k0, Bd1);
    __syncthreads();                       // vmcnt(0) drain -> LDS tile ready
    bfrag af[4], bf_[4];
#pragma unroll
    for (int mt = 0; mt < 4; mt++)
      af[mt] = *(const bfrag*)(As + (wm + mt * 16 + lrow) * 32 + quad * 8);
#pragma unroll
    for (int nt = 0; nt < 4; nt++)
      bf_[nt] = *(const bfrag*)(Bs + (wn + nt * 16 + lrow) * 32 + quad * 8);
#pragma unroll
    for (int mt = 0; mt < 4; mt++)
#pragma unroll
      for (int nt = 0; nt < 4; nt++)
        acc[mt][nt] = __builtin_amdgcn_mfma_f32_16x16x32_bf16(af[mt], bf_[nt], acc[mt][nt], 0, 0, 0);
  }
}

// ---------------------------------------------------------------- projections
struct ProjArgs {
  const unsigned short* X[5];
  const unsigned short* W[5];
  const float* bias[5];
  unsigned short* dst[5];
};

__global__ __launch_bounds__(256) void proj_kernel(ProjArgs pa) {
  __shared__ unsigned short As[128 * 32];
  __shared__ unsigned short Bs[128 * 32];
  const int z = blockIdx.z;
  const int m0 = blockIdx.y * 128, n0 = blockIdx.x * 128;
  f32x4 acc[4][4];
#pragma unroll
  for (int mt = 0; mt < 4; mt++)
#pragma unroll
    for (int nt = 0; nt < 4; nt++) acc[mt][nt] = (f32x4)0.f;

  mm128_core<E_>(pa.X[z], pa.W[z], m0, n0, As, Bs, acc);

  const int tid = threadIdx.x, lane = tid & 63, w = tid >> 6;
  const int lrow = lane & 15, quad = lane >> 4;
  const int wm = (w >> 1) * 64, wn = (w & 1) * 64;
  const float* __restrict__ bias = pa.bias[z];
  unsigned short* __restrict__ dst = pa.dst[z];
  float bv[4];
#pragma unroll
  for (int nt = 0; nt < 4; nt++) bv[nt] = bias[n0 + wn + nt * 16 + lrow];
#pragma unroll
  for (int mt = 0; mt < 4; mt++)
#pragma unroll
    for (int nt = 0; nt < 4; nt++)
#pragma unroll
      for (int ii = 0; ii < 4; ii++) {
        const int m = m0 + wm + mt * 16 + quad * 4 + ii;    // (b,t)
        const int n = n0 + wn + nt * 16 + lrow;             // (h,d)
        const float v = acc[mt][nt][ii] + bv[nt];
        const int b = m >> 10, t = m & 1023, h = n >> 6, dd = n & 63;
        size_t idx;
        if (z == 4)  // V transposed: [bh][d][t]
          idx = ((size_t)((b * H_ + h) * HD_ + dd)) * T_ + t;
        else         // Q/K: [bh][t][d]
          idx = ((size_t)((b * H_ + h) * T_ + t)) * HD_ + dd;
        dst[idx] = f2b(v);
      }
}

// ---------------------------------------------------------------- sum pass
// grid (8 t-tiles, 4 s-quarters, 32 bh) = 1024 blocks -> 4 blocks/CU, no LDS,
// VGPR <= 128 -> 4 waves/SIMD. i-outer with Q-frag hoist.
__global__ __launch_bounds__(256, 4) void attn_sums_kernel(
    const unsigned short* __restrict__ Q1, const unsigned short* __restrict__ Q2,
    const unsigned short* __restrict__ Q3, const unsigned short* __restrict__ Kh,
    float* __restrict__ sums) {
  const int flat = blockIdx.x + 8 * (blockIdx.y + 4 * blockIdx.z);   // 0..1023
  const int swz  = (flat & 7) * 128 + (flat >> 3);                   // bijective
  const int bx   = swz & 7;
  const int sy   = (swz >> 3) & 3;
  const int bh   = swz >> 5;

  const int tid = threadIdx.x, lane = tid & 63, w = tid >> 6;
  const int lrow = lane & 15, quad = lane >> 4;
  const int tw = w >> 1, sw = w & 1;
  const int tb = bx * 128 + tw * 64;
  const int sbase = sy * 256;
  const size_t base = (size_t)bh * T_ * HD_;
  const unsigned short* Qs[3] = {Q1 + base, Q2 + base, Q3 + base};
  const unsigned short* Kb = Kh + base;

  float ls[3][2];
#pragma unroll
  for (int i = 0; i < 3; i++) { ls[i][0] = 0.f; ls[i][1] = 0.f; }

#pragma unroll
  for (int i = 0; i < 3; i++) {
    // hoist Q fragments for this i (8 bfrags, reused across both j-tiles)
    bfrag qf[2][4];
#pragma unroll
    for (int kk = 0; kk < 2; kk++)
#pragma unroll
      for (int mt = 0; mt < 4; mt++)
        qf[kk][mt] = *(const bfrag*)(Qs[i] + (size_t)(tb + mt * 16 + lrow) * HD_ + kk * 32 + quad * 8);
#pragma unroll
    for (int j = 0; j < 2; j++) {
      const int sb = sbase + j * 128 + sw * 64;
      f32x4 acc[4][4];
#pragma unroll
      for (int mt = 0; mt < 4; mt++)
#pragma unroll
        for (int nt = 0; nt < 4; nt++) acc[mt][nt] = (f32x4)0.f;
#pragma unroll
      for (int kk = 0; kk < 2; kk++) {
        bfrag bf_[4];
#pragma unroll
        for (int nt = 0; nt < 4; nt++)
          bf_[nt] = *(const bfrag*)(Kb + (size_t)(sb + nt * 16 + lrow) * HD_ + kk * 32 + quad * 8);
#pragma unroll
        for (int mt = 0; mt < 4; mt++)
#pragma unroll
          for (int nt = 0; nt < 4; nt++)
            acc[mt][nt] = __builtin_amdgcn_mfma_f32_16x16x32_bf16(qf[kk][mt], bf_[nt], acc[mt][nt], 0, 0, 0);
      }
#pragma unroll
      for (int mt = 0; mt < 4; mt++)
#pragma unroll
        for (int nt = 0; nt < 4; nt++)
#pragma unroll
          for (int ii = 0; ii < 4; ii++)
            ls[i][ii & 1] += fexp2(acc[mt][nt][ii] * CEXP);
    }
  }
#pragma unroll
  for (int i = 0; i < 3; i++) {
    float v = ls[i][0] + ls[i][1];
    for (int off = 32; off > 0; off >>= 1) v += __shfl_down(v, off, 64);
    if (lane == 0) atomicAdd(&sums[i * BH_ + bh], v);
  }
}

// ---------------------------------------------------------------- main attention
// grid (8 t-tiles, 3 i, 32 bh) = 768 blocks -> 3 blocks/CU, 3 waves/SIMD.
// Each block: one Q-matrix, full s range. No pc accumulation; P = r*e direct.
// a1 written by i==0 blocks. O_i partial -> attnP[i]; combined later.
__global__ __launch_bounds__(256, 3) void attn_main_kernel(
    const unsigned short* __restrict__ Q1, const unsigned short* __restrict__ Q2,
    const unsigned short* __restrict__ Q3, const unsigned short* __restrict__ Kh,
    const unsigned short* __restrict__ Vt, const float* __restrict__ sums,
    float* __restrict__ a1out, unsigned short* __restrict__ attnP) {
  __shared__ unsigned short P[128 * 136];   // stride 136: 16B-aligned rows
  const int flat = blockIdx.x + 8 * (blockIdx.y + 3 * blockIdx.z);   // 0..767
  const int swz  = (flat & 7) * 96 + (flat >> 3);                    // bijective
  const int bh   = swz / 24;
  const int rem  = swz % 24;
  const int iq   = rem >> 3;
  const int bx   = rem & 7;

  const int tid = threadIdx.x, lane = tid & 63, w = tid >> 6;
  const int lrow = lane & 15, quad = lane >> 4;
  const int tw = w >> 1, sw = w & 1, dw = sw;
  const int b = bh >> 4, h = bh & 15;
  const int tb = bx * 128 + tw * 64;
  const size_t base = (size_t)bh * T_ * HD_;
  const unsigned short* Qb = (iq == 0 ? Q1 : (iq == 1 ? Q2 : Q3)) + base;
  const unsigned short* Kb = Kh + base;
  const unsigned short* Vb = Vt + (size_t)bh * HD_ * T_;
  unsigned short* __restrict__ dst = attnP + (size_t)iq * (2048 * 1024);

  const float r = (float)T_ / (3.f * sums[iq * BH_ + bh]);
  const float a1s = 3.f * r;                 // used only when iq==0

  // hoist Q fragments (reused across all 8 s-tiles)
  bfrag qf[2][4];
#pragma unroll
  for (int kk = 0; kk < 2; kk++)
#pragma unroll
    for (int mt = 0; mt < 4; mt++)
      qf[kk][mt] = *(const bfrag*)(Qb + (size_t)(tb + mt * 16 + lrow) * HD_ + kk * 32 + quad * 8);

  f32x4 oacc[4][2];
#pragma unroll
  for (int mt = 0; mt < 4; mt++) { oacc[mt][0] = (f32x4)0.f; oacc[mt][1] = (f32x4)0.f; }

  for (int s0 = 0; s0 < T_; s0 += 128) {
    const int sb = s0 + sw * 64;
    f32x4 acc[4][4];
#pragma unroll
    for (int mt = 0; mt < 4; mt++)
#pragma unroll
      for (int nt = 0; nt < 4; nt++) acc[mt][nt] = (f32x4)0.f;
#pragma unroll
    for (int kk = 0; kk < 2; kk++) {
      bfrag bf_[4];
#pragma unroll
      for (int nt = 0; nt < 4; nt++)
        bf_[nt] = *(const bfrag*)(Kb + (size_t)(sb + nt * 16 + lrow) * HD_ + kk * 32 + quad * 8);
#pragma unroll
      for (int mt = 0; mt < 4; mt++)
#pragma unroll
        for (int nt = 0; nt < 4; nt++)
          acc[mt][nt] = __builtin_amdgcn_mfma_f32_16x16x32_bf16(qf[kk][mt], bf_[nt], acc[mt][nt], 0, 0, 0);
    }
    __syncthreads();   // prev-iter P reads complete
#pragma unroll
    for (int mt = 0; mt < 4; mt++)
#pragma unroll
      for (int nt = 0; nt < 4; nt++)
#pragma unroll
        for (int ii = 0; ii < 4; ii++) {
          const float e = fexp2(acc[mt][nt][ii] * CEXP);
          const int tl = tw * 64 + mt * 16 + quad * 4 + ii;
          const int sl = sw * 64 + nt * 16 + lrow;
          P[tl * 136 + sl] = f2b(r * e);
          if (iq == 0) {
            __builtin_nontemporal_store(e * a1s,
                a1out + ((size_t)bh * T_ + (tb - tw * 64 + tl)) * T_ + s0 + sl);
          }
        }
    __syncthreads();   // P ready
    // PV: wave covers t[tw*64 .. +63] x d[dw*32 .. +31]
#pragma unroll
    for (int kk = 0; kk < 4; kk++) {
      bfrag pf[4], vf[2];
#pragma unroll
      for (int mt = 0; mt < 4; mt++)
        pf[mt] = *(const bfrag*)(P + (tw * 64 + mt * 16 + lrow) * 136 + kk * 32 + quad * 8);
#pragma unroll
      for (int nt = 0; nt < 2; nt++)
        vf[nt] = *(const bfrag*)(Vb + (size_t)(dw * 32 + nt * 16 + lrow) * T_ + s0 + kk * 32 + quad * 8);
#pragma unroll
      for (int mt = 0; mt < 4; mt++)
#pragma unroll
        for (int nt = 0; nt < 2; nt++)
          oacc[mt][nt] = __builtin_amdgcn_mfma_f32_16x16x32_bf16(pf[mt], vf[nt], oacc[mt][nt], 0, 0, 0);
    }
  }
  // partial O_i -> attnP[iq] [b*T+t][h*64+dd] bf16
#pragma unroll
  for (int mt = 0; mt < 4; mt++)
#pragma unroll
    for (int nt = 0; nt < 2; nt++)
#pragma unroll
      for (int ii = 0; ii < 4; ii++) {
        const int t = tb + mt * 16 + quad * 4 + ii;
        const int dd = dw * 32 + nt * 16 + lrow;
        dst[((size_t)(b * T_ + t)) * E_ + h * HD_ + dd] = f2b(oacc[mt][nt][ii]);
      }
}

// ---------------------------------------------------------------- combine
// attn = sum of 3 bf16 partials (fp32 add). 16 MB traffic.
__global__ __launch_bounds__(256) void combine_kernel(
    const unsigned short* __restrict__ p0, const unsigned short* __restrict__ p1,
    const unsigned short* __restrict__ p2, unsigned short* __restrict__ dstc) {
  const size_t i = ((size_t)blockIdx.x * 256 + threadIdx.x) * 8;
  bfrag a = *(const bfrag*)(p0 + i);
  bfrag b = *(const bfrag*)(p1 + i);
  bfrag c = *(const bfrag*)(p2 + i);
  bfrag o;
#pragma unroll
  for (int j = 0; j < 8; j++) {
    const float f = b2f((unsigned short)a[j]) + b2f((unsigned short)b[j]) +
                    b2f((unsigned short)c[j]);
    o[j] = (short)f2b(f);
  }
  *(bfrag*)(dstc + i) = o;
}

// ---------------------------------------------------------------- output projection
__global__ __launch_bounds__(256) void outproj_kernel(
    const unsigned short* __restrict__ Ab, const unsigned short* __restrict__ Wb,
    const float* __restrict__ bias, float* __restrict__ out) {
  __shared__ unsigned short As[128 * 32];
  __shared__ unsigned short Bs[128 * 32];
  const int m0 = blockIdx.y * 128, n0 = blockIdx.x * 128;
  f32x4 acc[4][4];
#pragma unroll
  for (int mt = 0; mt < 4; mt++)
#pragma unroll
    for (int nt = 0; nt < 4; nt++) acc[mt][nt] = (f32x4)0.f;

  mm128_core<E_>(Ab, Wb, m0, n0, As, Bs, acc);

  const int tid = threadIdx.x, lane = tid & 63, w = tid >> 6;
  const int lrow = lane & 15, quad = lane >> 4;
  const int wm = (w >> 1) * 64, wn = (w & 1) * 64;
  float bv[4];
#pragma unroll
  for (int nt = 0; nt < 4; nt++) bv[nt] = bias[n0 + wn + nt * 16 + lrow];
#pragma unroll
  for (int mt = 0; mt < 4; mt++)
#pragma unroll
    for (int nt = 0; nt < 4; nt++)
#pragma unroll
      for (int ii = 0; ii < 4; ii++) {
        const int m = m0 + wm + mt * 16 + quad * 4 + ii;
        const int n = n0 + wn + nt * 16 + lrow;
        out[(size_t)m * E_ + n] = acc[mt][nt][ii] + bv[nt];
      }
}

// ---------------------------------------------------------------- launcher
extern "C" void kernel_launch(void* const* d_in, const int* in_sizes, int n_in,
                              void* d_out, int out_size, void* d_ws, size_t ws_size,
                              hipStream_t stream) {
  const float* q1f  = (const float*)d_in[0];
  const float* q2f  = (const float*)d_in[1];
  const float* keyf = (const float*)d_in[2];
  const float* valf = (const float*)d_in[3];
  const float* Wq  = (const float*)d_in[4];  const float* bq  = (const float*)d_in[5];
  const float* Wq2 = (const float*)d_in[6];  const float* bq2 = (const float*)d_in[7];
  const float* Wq3 = (const float*)d_in[8];  const float* bq3 = (const float*)d_in[9];
  const float* Wk  = (const float*)d_in[10]; const float* bk  = (const float*)d_in[11];
  const float* Wv  = (const float*)d_in[12]; const float* bv  = (const float*)d_in[13];
  const float* Wo  = (const float*)d_in[14]; const float* bo  = (const float*)d_in[15];

  char* ws = (char*)d_ws;
  const size_t MB = 1024 * 1024;
  // 0..16MB: bf16 inputs during proj; reused as attnP partials afterwards.
  unsigned short* xq1  = (unsigned short*)(ws + 0 * MB);
  unsigned short* xq2  = (unsigned short*)(ws + 4 * MB);
  unsigned short* xkey = (unsigned short*)(ws + 8 * MB);
  unsigned short* xval = (unsigned short*)(ws + 12 * MB);
  unsigned short* wq   = (unsigned short*)(ws + 16 * MB);
  unsigned short* wq2  = (unsigned short*)(ws + 18 * MB);
  unsigned short* wq3  = (unsigned short*)(ws + 20 * MB);
  unsigned short* wk   = (unsigned short*)(ws + 22 * MB);
  unsigned short* wv   = (unsigned short*)(ws + 24 * MB);
  unsigned short* wo   = (unsigned short*)(ws + 26 * MB);
  unsigned short* Qh1  = (unsigned short*)(ws + 28 * MB);
  unsigned short* Qh2  = (unsigned short*)(ws + 32 * MB);
  unsigned short* Qh3  = (unsigned short*)(ws + 36 * MB);
  unsigned short* Kh   = (unsigned short*)(ws + 40 * MB);
  unsigned short* Vt   = (unsigned short*)(ws + 44 * MB);
  unsigned short* attnP = (unsigned short*)(ws + 48 * MB);  // 3 x 4MB partials
  unsigned short* attn  = (unsigned short*)(ws + 60 * MB);  // 4MB combined
  float* sums           = (float*)(ws + 64 * MB);

  // 1) fp32 -> bf16
  CvtArgs ca;
  const float* srcs[10] = {q1f, q2f, keyf, valf, Wq, Wq2, Wq3, Wk, Wv, Wo};
  unsigned short* dsts[10] = {xq1, xq2, xkey, xval, wq, wq2, wq3, wk, wv, wo};
  for (int i = 0; i < 10; i++) { ca.src[i] = srcs[i]; ca.dst[i] = dsts[i]; ca.n[i] = (i < 4) ? 2097152 : 1048576; }
  cvt_kernel<<<dim3(2048, 10), 256, 0, stream>>>(ca);

  hipMemsetAsync(sums, 0, 3 * BH_ * sizeof(float), stream);

  // 2) projections -> head layouts (V transposed)
  ProjArgs pa;
  const unsigned short* Xs[5] = {xq1, xq2, xkey, xkey, xval};
  const unsigned short* Ws_[5] = {wq, wq2, wq3, wk, wv};
  const float* Bi[5] = {bq, bq2, bq3, bk, bv};
  unsigned short* Ds[5] = {Qh1, Qh2, Qh3, Kh, Vt};
  for (int i = 0; i < 5; i++) { pa.X[i] = Xs[i]; pa.W[i] = Ws_[i]; pa.bias[i] = Bi[i]; pa.dst[i] = Ds[i]; }
  proj_kernel<<<dim3(8, 16, 5), 256, 0, stream>>>(pa);

  // 3) global softmax denominators
  attn_sums_kernel<<<dim3(8, 4, BH_), 256, 0, stream>>>(Qh1, Qh2, Qh3, Kh, sums);

  // 4) attention: a1 + per-i partial PV (i-split; overwrites dead x* buffers)
  float* out = (float*)d_out;
  attn_main_kernel<<<dim3(8, 3, BH_), 256, 0, stream>>>(Qh1, Qh2, Qh3, Kh, Vt, sums,
                                                        out + 2097152, attnP);

  // 5) combine the 3 partials
  combine_kernel<<<dim3(1024), 256, 0, stream>>>(attnP, attnP + 4 * MB / 2,
                                                 attnP + 8 * MB / 2, attn);

  // 6) output projection (K=1024)
  outproj_kernel<<<dim3(8, 16), 256, 0, stream>>>(attn, wo, bo, out);
}

// Round 6
// 374.082 us; speedup vs baseline: 1.6111x; 1.6111x over previous
//
#include <hip/hip_runtime.h>
#include <hip/hip_bf16.h>

// SimpleMultiheadAttention on gfx950.
// d_in: 0 query1,1 query2,2 key,3 value, then (Wq,bq),(Wq2,bq2),(Wq3,bq3),(Wk,bk),(Wv,bv),(Wo,bo)
// d_out: output [2,1024,1024] fp32 then a1 [2,16,1024,1024] fp32.
// bf16 MFMA everywhere; global softmax via sum-pass + recompute-pass.
// R6: R5 with the combine2 pointer fix (second partial is at +2097152 ELEMENTS
// = +4MB; R5 passed +2097152*2 which aliased the combine output buffer).

#define B_ 2
#define T_ 1024
#define E_ 1024
#define H_ 16
#define HD_ 64
#define BH_ 32

// 0.125 (1/sqrt(64)) / 0.5 (TEMP) * log2(e)
#define CEXP 0.36067376022224085f

typedef float f32x4 __attribute__((ext_vector_type(4)));
typedef short bfrag __attribute__((ext_vector_type(8)));   // 8 x bf16

__device__ __forceinline__ unsigned short f2b(float f) {
  unsigned int u = __float_as_uint(f);
  u += 0x7fffu + ((u >> 16) & 1u);          // RNE (inputs finite)
  return (unsigned short)(u >> 16);
}

__device__ __forceinline__ float b2f(unsigned short u) {
  return __uint_as_float((unsigned int)u << 16);
}

// single-instruction 2^x (inputs finite; library exp2f's edge handling not needed)
__device__ __forceinline__ float fexp2(float x) {
  float r;
  asm("v_exp_f32 %0, %1" : "=v"(r) : "v"(x));
  return r;
}

// global -> LDS direct 16B copy.
__device__ __forceinline__ void gl_lds16(const unsigned short* g, unsigned short* l) {
  __builtin_amdgcn_global_load_lds(
      reinterpret_cast<const __attribute__((address_space(1))) unsigned int*>(
          reinterpret_cast<uintptr_t>(g)),
      reinterpret_cast<__attribute__((address_space(3))) unsigned int*>(
          reinterpret_cast<uintptr_t>(l)),
      16, 0, 0);
}

// ---------------------------------------------------------------- convert
struct CvtArgs { const float* src[10]; unsigned short* dst[10]; int n[10]; };

__global__ __launch_bounds__(256) void cvt_kernel(CvtArgs a) {
  const int z = blockIdx.y;
  const float* __restrict__ s = a.src[z];
  unsigned short* __restrict__ d = a.dst[z];
  const int n = a.n[z];
  const int stride = gridDim.x * 256 * 4;
  for (int i = (blockIdx.x * 256 + threadIdx.x) * 4; i < n; i += stride) {
    float4 v = *(const float4*)(s + i);
    ushort4 o;
    o.x = f2b(v.x); o.y = f2b(v.y); o.z = f2b(v.z); o.w = f2b(v.w);
    *(ushort4*)(d + i) = o;
  }
}

// ---------------------------------------------------------------- GEMM core
// C[128x128] tile of A * W^T (both row-major [row][KLEN] bf16).
// m97 structure: global_load_lds dwordx4 stage -> drain barrier -> ds_read+MFMA.
template <int KLEN>
__device__ __forceinline__ void mm128_core(const unsigned short* __restrict__ A,
                                           const unsigned short* __restrict__ W,
                                           int m0, int n0,
                                           unsigned short* As, unsigned short* Bs,
                                           f32x4 acc[4][4]) {
  const int tid  = threadIdx.x;
  const int lane = tid & 63, w = tid >> 6;
  const int lrow = lane & 15, quad = lane >> 4;
  const int wm = (w >> 1) * 64, wn = (w & 1) * 64;
  const int srow = tid >> 2, soff = (tid & 3) * 8;   // 8 bf16 = 16B per load

  const unsigned short* Ar0 = A + (size_t)(m0 + srow) * KLEN + soff;
  const unsigned short* Ar1 = Ar0 + (size_t)64 * KLEN;
  const unsigned short* Br0 = W + (size_t)(n0 + srow) * KLEN + soff;
  const unsigned short* Br1 = Br0 + (size_t)64 * KLEN;
  unsigned short* Ad0 = As + tid * 8;
  unsigned short* Ad1 = As + 2048 + tid * 8;
  unsigned short* Bd0 = Bs + tid * 8;
  unsigned short* Bd1 = Bs + 2048 + tid * 8;

  for (int k0 = 0; k0 < KLEN; k0 += 32) {
    __syncthreads();                       // prev-iter LDS reads done
    gl_lds16(Ar0 + k0, Ad0);
    gl_lds16(Ar1 + k0, Ad1);
    gl_lds16(Br0 + k0, Bd0);
    gl_lds16(Br1 + k0, Bd1);
    __syncthreads();                       // vmcnt(0) drain -> LDS tile ready
    bfrag af[4], bf_[4];
#pragma unroll
    for (int mt = 0; mt < 4; mt++)
      af[mt] = *(const bfrag*)(As + (wm + mt * 16 + lrow) * 32 + quad * 8);
#pragma unroll
    for (int nt = 0; nt < 4; nt++)
      bf_[nt] = *(const bfrag*)(Bs + (wn + nt * 16 + lrow) * 32 + quad * 8);
#pragma unroll
    for (int mt = 0; mt < 4; mt++)
#pragma unroll
      for (int nt = 0; nt < 4; nt++)
        acc[mt][nt] = __builtin_amdgcn_mfma_f32_16x16x32_bf16(af[mt], bf_[nt], acc[mt][nt], 0, 0, 0);
  }
}

// ---------------------------------------------------------------- projections
struct ProjArgs {
  const unsigned short* X[5];
  const unsigned short* W[5];
  const float* bias[5];
  unsigned short* dst[5];
};

__global__ __launch_bounds__(256) void proj_kernel(ProjArgs pa) {
  __shared__ unsigned short As[128 * 32];
  __shared__ unsigned short Bs[128 * 32];
  const int z = blockIdx.z;
  const int m0 = blockIdx.y * 128, n0 = blockIdx.x * 128;
  f32x4 acc[4][4];
#pragma unroll
  for (int mt = 0; mt < 4; mt++)
#pragma unroll
    for (int nt = 0; nt < 4; nt++) acc[mt][nt] = (f32x4)0.f;

  mm128_core<E_>(pa.X[z], pa.W[z], m0, n0, As, Bs, acc);

  const int tid = threadIdx.x, lane = tid & 63, w = tid >> 6;
  const int lrow = lane & 15, quad = lane >> 4;
  const int wm = (w >> 1) * 64, wn = (w & 1) * 64;
  const float* __restrict__ bias = pa.bias[z];
  unsigned short* __restrict__ dst = pa.dst[z];
  float bv[4];
#pragma unroll
  for (int nt = 0; nt < 4; nt++) bv[nt] = bias[n0 + wn + nt * 16 + lrow];
#pragma unroll
  for (int mt = 0; mt < 4; mt++)
#pragma unroll
    for (int nt = 0; nt < 4; nt++)
#pragma unroll
      for (int ii = 0; ii < 4; ii++) {
        const int m = m0 + wm + mt * 16 + quad * 4 + ii;    // (b,t)
        const int n = n0 + wn + nt * 16 + lrow;             // (h,d)
        const float v = acc[mt][nt][ii] + bv[nt];
        const int b = m >> 10, t = m & 1023, h = n >> 6, dd = n & 63;
        size_t idx;
        if (z == 4)  // V transposed: [bh][d][t]
          idx = ((size_t)((b * H_ + h) * HD_ + dd)) * T_ + t;
        else         // Q/K: [bh][t][d]
          idx = ((size_t)((b * H_ + h) * T_ + t)) * HD_ + dd;
        dst[idx] = f2b(v);
      }
}

// ---------------------------------------------------------------- sum pass
// grid (8 t-tiles of 128, 2 s-halves, 32 bh) = 512 blocks -> 2 blocks/CU.
// No launch_bounds arg2: VGPRs stay at natural allocation (no spills).
__global__ __launch_bounds__(256) void attn_sums_kernel(
    const unsigned short* __restrict__ Q1, const unsigned short* __restrict__ Q2,
    const unsigned short* __restrict__ Q3, const unsigned short* __restrict__ Kh,
    float* __restrict__ sums) {
  const int flat = blockIdx.x + 8 * (blockIdx.y + 2 * blockIdx.z);   // 0..511
  const int swz  = (flat & 7) * 64 + (flat >> 3);                    // bijective
  const int bx   = swz & 7;
  const int shalf = (swz >> 3) & 1;
  const int bh   = swz >> 4;

  const int tid = threadIdx.x, lane = tid & 63, w = tid >> 6;
  const int lrow = lane & 15, quad = lane >> 4;
  const int tw = w >> 1, sw = w & 1;
  const int tb = bx * 128 + tw * 64;
  const int sbase = shalf * 512;
  const size_t base = (size_t)bh * T_ * HD_;
  const unsigned short* Qs[3] = {Q1 + base, Q2 + base, Q3 + base};
  const unsigned short* Kb = Kh + base;

  float ls[3][4];
#pragma unroll
  for (int i = 0; i < 3; i++)
#pragma unroll
    for (int ii = 0; ii < 4; ii++) ls[i][ii] = 0.f;

  for (int j = 0; j < 4; j++) {
    const int sb = sbase + j * 128 + sw * 64;
#pragma unroll
    for (int i = 0; i < 3; i++) {
      f32x4 acc[4][4];
#pragma unroll
      for (int mt = 0; mt < 4; mt++)
#pragma unroll
        for (int nt = 0; nt < 4; nt++) acc[mt][nt] = (f32x4)0.f;
#pragma unroll
      for (int kk = 0; kk < 2; kk++) {
        bfrag af[4], bf_[4];
#pragma unroll
        for (int mt = 0; mt < 4; mt++)
          af[mt] = *(const bfrag*)(Qs[i] + (size_t)(tb + mt * 16 + lrow) * HD_ + kk * 32 + quad * 8);
#pragma unroll
        for (int nt = 0; nt < 4; nt++)
          bf_[nt] = *(const bfrag*)(Kb + (size_t)(sb + nt * 16 + lrow) * HD_ + kk * 32 + quad * 8);
#pragma unroll
        for (int mt = 0; mt < 4; mt++)
#pragma unroll
          for (int nt = 0; nt < 4; nt++)
            acc[mt][nt] = __builtin_amdgcn_mfma_f32_16x16x32_bf16(af[mt], bf_[nt], acc[mt][nt], 0, 0, 0);
      }
#pragma unroll
      for (int mt = 0; mt < 4; mt++)
#pragma unroll
        for (int nt = 0; nt < 4; nt++)
#pragma unroll
          for (int ii = 0; ii < 4; ii++)
            ls[i][ii] += fexp2(acc[mt][nt][ii] * CEXP);
    }
  }
#pragma unroll
  for (int i = 0; i < 3; i++) {
    float v = (ls[i][0] + ls[i][1]) + (ls[i][2] + ls[i][3]);
    for (int off = 32; off > 0; off >>= 1) v += __shfl_down(v, off, 64);
    if (lane == 0) atomicAdd(&sums[i * BH_ + bh], v);
  }
}

// ---------------------------------------------------------------- main attention
// grid (8 t-tiles of 128, 2 s-halves, 32 bh) = 512 blocks -> 2 blocks/CU.
// Each block: QK^T+exp over its 512 s-cols, a1 writes (disjoint), partial PV
// into attnP[sh] [2048][1024] bf16 (combined by combine2 + K=1024 outproj).
__global__ __launch_bounds__(256) void attn_main_kernel(
    const unsigned short* __restrict__ Q1, const unsigned short* __restrict__ Q2,
    const unsigned short* __restrict__ Q3, const unsigned short* __restrict__ Kh,
    const unsigned short* __restrict__ Vt, const float* __restrict__ sums,
    float* __restrict__ a1out, unsigned short* __restrict__ attnP) {
  __shared__ unsigned short P[128 * 136];   // stride 136: 16B-aligned rows
  const int flat = blockIdx.x + 8 * (blockIdx.y + 2 * blockIdx.z);   // 0..511
  const int swz  = (flat & 7) * 64 + (flat >> 3);                    // bijective
  const int bx   = swz & 7;
  const int sh   = (swz >> 3) & 1;
  const int bh   = swz >> 4;

  const int tid = threadIdx.x, lane = tid & 63, w = tid >> 6;
  const int lrow = lane & 15, quad = lane >> 4;
  const int tw = w >> 1, sw = w & 1, dw = sw;
  const int b = bh >> 4, h = bh & 15;
  const int tb = bx * 128 + tw * 64;
  const size_t base = (size_t)bh * T_ * HD_;
  const unsigned short* Qs[3] = {Q1 + base, Q2 + base, Q3 + base};
  const unsigned short* Kb = Kh + base;
  const unsigned short* Vb = Vt + (size_t)bh * HD_ * T_;
  unsigned short* __restrict__ dst = attnP + (size_t)sh * (2048u * 1024u);

  float r[3];
#pragma unroll
  for (int i = 0; i < 3; i++) r[i] = (float)T_ / (3.f * sums[i * BH_ + bh]);
  const float a1s = 3.f * r[0];

  f32x4 oacc[4][2];
#pragma unroll
  for (int mt = 0; mt < 4; mt++) { oacc[mt][0] = (f32x4)0.f; oacc[mt][1] = (f32x4)0.f; }

  for (int s0 = sh * 512; s0 < sh * 512 + 512; s0 += 128) {
    const int sb = s0 + sw * 64;
    f32x4 pc[4][4];
#pragma unroll
    for (int mt = 0; mt < 4; mt++)
#pragma unroll
      for (int nt = 0; nt < 4; nt++) pc[mt][nt] = (f32x4)0.f;

#pragma unroll
    for (int i = 0; i < 3; i++) {
      f32x4 acc[4][4];
#pragma unroll
      for (int mt = 0; mt < 4; mt++)
#pragma unroll
        for (int nt = 0; nt < 4; nt++) acc[mt][nt] = (f32x4)0.f;
#pragma unroll
      for (int kk = 0; kk < 2; kk++) {
        bfrag af[4], bf_[4];
#pragma unroll
        for (int mt = 0; mt < 4; mt++)
          af[mt] = *(const bfrag*)(Qs[i] + (size_t)(tb + mt * 16 + lrow) * HD_ + kk * 32 + quad * 8);
#pragma unroll
        for (int nt = 0; nt < 4; nt++)
          bf_[nt] = *(const bfrag*)(Kb + (size_t)(sb + nt * 16 + lrow) * HD_ + kk * 32 + quad * 8);
#pragma unroll
        for (int mt = 0; mt < 4; mt++)
#pragma unroll
          for (int nt = 0; nt < 4; nt++)
            acc[mt][nt] = __builtin_amdgcn_mfma_f32_16x16x32_bf16(af[mt], bf_[nt], acc[mt][nt], 0, 0, 0);
      }
      const float ri = r[i];
#pragma unroll
      for (int mt = 0; mt < 4; mt++)
#pragma unroll
        for (int nt = 0; nt < 4; nt++)
#pragma unroll
          for (int ii = 0; ii < 4; ii++) {
            const float e = fexp2(acc[mt][nt][ii] * CEXP);
            pc[mt][nt][ii] += ri * e;
            if (i == 0) {
              const int t = tb + mt * 16 + quad * 4 + ii;
              const int s = sb + nt * 16 + lrow;
              __builtin_nontemporal_store(e * a1s,
                  a1out + ((size_t)bh * T_ + t) * T_ + s);
            }
          }
    }
    __syncthreads();   // prev-iter P reads complete
#pragma unroll
    for (int mt = 0; mt < 4; mt++)
#pragma unroll
      for (int nt = 0; nt < 4; nt++)
#pragma unroll
        for (int ii = 0; ii < 4; ii++) {
          const int tl = tw * 64 + mt * 16 + quad * 4 + ii;
          const int sl = sw * 64 + nt * 16 + lrow;
          P[tl * 136 + sl] = f2b(pc[mt][nt][ii]);
        }
    __syncthreads();   // P ready
    // PV: wave covers t[tw*64 .. +63] x d[dw*32 .. +31]
#pragma unroll
    for (int kk = 0; kk < 4; kk++) {
      bfrag pf[4], vf[2];
#pragma unroll
      for (int mt = 0; mt < 4; mt++)
        pf[mt] = *(const bfrag*)(P + (tw * 64 + mt * 16 + lrow) * 136 + kk * 32 + quad * 8);
#pragma unroll
      for (int nt = 0; nt < 2; nt++)
        vf[nt] = *(const bfrag*)(Vb + (size_t)(dw * 32 + nt * 16 + lrow) * T_ + s0 + kk * 32 + quad * 8);
#pragma unroll
      for (int mt = 0; mt < 4; mt++)
#pragma unroll
        for (int nt = 0; nt < 2; nt++)
          oacc[mt][nt] = __builtin_amdgcn_mfma_f32_16x16x32_bf16(pf[mt], vf[nt], oacc[mt][nt], 0, 0, 0);
    }
  }
  // partial O (s-half sh) -> attnP[sh] [b*T+t][h*64+dd] bf16
#pragma unroll
  for (int mt = 0; mt < 4; mt++)
#pragma unroll
    for (int nt = 0; nt < 2; nt++)
#pragma unroll
      for (int ii = 0; ii < 4; ii++) {
        const int t = tb + mt * 16 + quad * 4 + ii;
        const int dd = dw * 32 + nt * 16 + lrow;
        dst[((size_t)(b * T_ + t)) * E_ + h * HD_ + dd] = f2b(oacc[mt][nt][ii]);
      }
}

// ---------------------------------------------------------------- combine
// attn = p0 + p1 (two s-half PV partials, fp32 add in bf16 storage). 12MB traffic.
__global__ __launch_bounds__(256) void combine2_kernel(
    const unsigned short* __restrict__ p0, const unsigned short* __restrict__ p1,
    unsigned short* __restrict__ dstc) {
  const size_t i = ((size_t)blockIdx.x * 256 + threadIdx.x) * 8;
  bfrag a = *(const bfrag*)(p0 + i);
  bfrag b = *(const bfrag*)(p1 + i);
  bfrag o;
#pragma unroll
  for (int j = 0; j < 8; j++) {
    const float f = b2f((unsigned short)a[j]) + b2f((unsigned short)b[j]);
    o[j] = (short)f2b(f);
  }
  *(bfrag*)(dstc + i) = o;
}

// ---------------------------------------------------------------- output projection
__global__ __launch_bounds__(256) void outproj_kernel(
    const unsigned short* __restrict__ Ab, const unsigned short* __restrict__ Wb,
    const float* __restrict__ bias, float* __restrict__ out) {
  __shared__ unsigned short As[128 * 32];
  __shared__ unsigned short Bs[128 * 32];
  const int m0 = blockIdx.y * 128, n0 = blockIdx.x * 128;
  f32x4 acc[4][4];
#pragma unroll
  for (int mt = 0; mt < 4; mt++)
#pragma unroll
    for (int nt = 0; nt < 4; nt++) acc[mt][nt] = (f32x4)0.f;

  mm128_core<E_>(Ab, Wb, m0, n0, As, Bs, acc);

  const int tid = threadIdx.x, lane = tid & 63, w = tid >> 6;
  const int lrow = lane & 15, quad = lane >> 4;
  const int wm = (w >> 1) * 64, wn = (w & 1) * 64;
  float bv[4];
#pragma unroll
  for (int nt = 0; nt < 4; nt++) bv[nt] = bias[n0 + wn + nt * 16 + lrow];
#pragma unroll
  for (int mt = 0; mt < 4; mt++)
#pragma unroll
    for (int nt = 0; nt < 4; nt++)
#pragma unroll
      for (int ii = 0; ii < 4; ii++) {
        const int m = m0 + wm + mt * 16 + quad * 4 + ii;
        const int n = n0 + wn + nt * 16 + lrow;
        out[(size_t)m * E_ + n] = acc[mt][nt][ii] + bv[nt];
      }
}

// ---------------------------------------------------------------- launcher
extern "C" void kernel_launch(void* const* d_in, const int* in_sizes, int n_in,
                              void* d_out, int out_size, void* d_ws, size_t ws_size,
                              hipStream_t stream) {
  const float* q1f  = (const float*)d_in[0];
  const float* q2f  = (const float*)d_in[1];
  const float* keyf = (const float*)d_in[2];
  const float* valf = (const float*)d_in[3];
  const float* Wq  = (const float*)d_in[4];  const float* bq  = (const float*)d_in[5];
  const float* Wq2 = (const float*)d_in[6];  const float* bq2 = (const float*)d_in[7];
  const float* Wq3 = (const float*)d_in[8];  const float* bq3 = (const float*)d_in[9];
  const float* Wk  = (const float*)d_in[10]; const float* bk  = (const float*)d_in[11];
  const float* Wv  = (const float*)d_in[12]; const float* bv  = (const float*)d_in[13];
  const float* Wo  = (const float*)d_in[14]; const float* bo  = (const float*)d_in[15];

  char* ws = (char*)d_ws;
  const size_t MB = 1024 * 1024;
  unsigned short* xq1  = (unsigned short*)(ws + 0 * MB);
  unsigned short* xq2  = (unsigned short*)(ws + 4 * MB);
  unsigned short* xkey = (unsigned short*)(ws + 8 * MB);
  unsigned short* xval = (unsigned short*)(ws + 12 * MB);
  unsigned short* wq   = (unsigned short*)(ws + 16 * MB);
  unsigned short* wq2  = (unsigned short*)(ws + 18 * MB);
  unsigned short* wq3  = (unsigned short*)(ws + 20 * MB);
  unsigned short* wk   = (unsigned short*)(ws + 22 * MB);
  unsigned short* wv   = (unsigned short*)(ws + 24 * MB);
  unsigned short* wo   = (unsigned short*)(ws + 26 * MB);
  unsigned short* Qh1  = (unsigned short*)(ws + 28 * MB);
  unsigned short* Qh2  = (unsigned short*)(ws + 32 * MB);
  unsigned short* Qh3  = (unsigned short*)(ws + 36 * MB);
  unsigned short* Kh   = (unsigned short*)(ws + 40 * MB);
  unsigned short* Vt   = (unsigned short*)(ws + 44 * MB);
  unsigned short* attnP = (unsigned short*)(ws + 48 * MB);  // 2 x 4MB s-half partials
  unsigned short* attn  = (unsigned short*)(ws + 56 * MB);  // 4MB combined
  float* sums           = (float*)(ws + 60 * MB);

  // 1) fp32 -> bf16
  CvtArgs ca;
  const float* srcs[10] = {q1f, q2f, keyf, valf, Wq, Wq2, Wq3, Wk, Wv, Wo};
  unsigned short* dsts[10] = {xq1, xq2, xkey, xval, wq, wq2, wq3, wk, wv, wo};
  for (int i = 0; i < 10; i++) { ca.src[i] = srcs[i]; ca.dst[i] = dsts[i]; ca.n[i] = (i < 4) ? 2097152 : 1048576; }
  cvt_kernel<<<dim3(2048, 10), 256, 0, stream>>>(ca);

  hipMemsetAsync(sums, 0, 3 * BH_ * sizeof(float), stream);

  // 2) projections -> head layouts (V transposed)
  ProjArgs pa;
  const unsigned short* Xs[5] = {xq1, xq2, xkey, xkey, xval};
  const unsigned short* Ws_[5] = {wq, wq2, wq3, wk, wv};
  const float* Bi[5] = {bq, bq2, bq3, bk, bv};
  unsigned short* Ds[5] = {Qh1, Qh2, Qh3, Kh, Vt};
  for (int i = 0; i < 5; i++) { pa.X[i] = Xs[i]; pa.W[i] = Ws_[i]; pa.bias[i] = Bi[i]; pa.dst[i] = Ds[i]; }
  proj_kernel<<<dim3(8, 16, 5), 256, 0, stream>>>(pa);

  // 3) global softmax denominators
  attn_sums_kernel<<<dim3(8, 2, BH_), 256, 0, stream>>>(Qh1, Qh2, Qh3, Kh, sums);

  // 4) attention: a1 + s-half PV partials
  float* out = (float*)d_out;
  attn_main_kernel<<<dim3(8, 2, BH_), 256, 0, stream>>>(Qh1, Qh2, Qh3, Kh, Vt, sums,
                                                        out + 2097152, attnP);

  // 5) combine the 2 partials (second partial is +2097152 ELEMENTS = +4MB)
  combine2_kernel<<<dim3(1024), 256, 0, stream>>>(attnP, attnP + 2097152, attn);

  // 6) output projection (K=1024)
  outproj_kernel<<<dim3(8, 16), 256, 0, stream>>>(attn, wo, bo, out);
}